// Round 5
// baseline (288.657 us; speedup 1.0000x reference)
//
#include <hip/hip_runtime.h>
#include <stdint.h>

// PoolingNms: 3 chained pool/unpool passes (k=3,5,6) on 16x1x1080x1920 fp32.
// lcm(3,5,6)=30 -> every 30-row stripe x 30-col segment is independent.
//
// Round 0-4 post-mortem: three different LDS-staged structures (5 blk/CU
// unpipelined; 2 blk/CU pipelined serial-window; 2 blk/CU pipelined
// register-resident) ALL land at 96-100us / ~2.05 TB/s. The only rate mover
// across rounds was resident-wave count (R1: 75% occ -> 2.6 TB/s). The
// barriers + LDS staging keep waves in lockstep with ~90% memory-idle duty
// cycle; the compute was never the limiter.
//
// Round 5: NO LDS, NO barriers. Wave-autonomous processing:
//  - lane = row (r = lane&31, rows 0..29 active; lanes 30,31 masked off),
//    half-wave h = lane>>5 owns one 30-col segment -> wave = 30x60 region,
//    entirely register-resident (v[30] per lane).
//  - loads/stores: per-lane contiguous 120 B as 7xfloat4 + float2. Segment
//    byte offsets are 240*bx*4 + w*240 + h*120 -> h=0 starts 16B-aligned,
//    h=1 starts 8 mod 16 (float2 first, then 16B-aligned float4s). All
//    vector accesses natural-aligned by construction.
//  - vertical K-max via __shfl over K consecutive lanes (rows of the
//    window group). Per-window scalars (hm,m,fr) die each iteration ->
//    low VGPR -> high occupancy.
//  - write-merge safety (round-1 lesson: cross-XCD partial lines amplify
//    WRITE_SIZE 1.2x): block covers 240 contiguous cols = 960 B/row = 15
//    whole cache lines; block boundaries line-aligned; all partial-line
//    sharers are waves of the SAME block (same CU -> same XCD L2) -> merge.
// Tie semantics (== jnp.argmax first-occurrence, row-major): first row via
// ascending strict-'>' scan of row-maxes, first col via seen-flag scan.
// Same algebra as round 4 (passed absmax=0), exchange via shuffles.

#define IMG_H 1080
#define IMG_W 1920

template <int K>
__device__ __forceinline__ void stage(float (&v)[30], int rc, int h) {
    constexpr int NH = 30 / K;          // windows along the 30-col segment
    const int g = rc / K;               // my row-group
    const int myrr = rc - g * K;        // my row within the group
    const int srcbase = (h << 5) + g * K;  // lane of group row 0 (<= 29 +32h)
#pragma unroll
    for (int j = 0; j < NH; ++j) {
        // horizontal K-max of my row's window j (thread-local)
        float hm = v[j * K];
#pragma unroll
        for (int c = 1; c < K; ++c) hm = fmaxf(hm, v[j * K + c]);
        // vertical: gather K row-maxes from consecutive lanes, ascending ->
        // strict '>' keeps the FIRST row achieving the window max.
        float m = -1.0f;                // inputs are >= 0
        int fr = -1;
#pragma unroll
        for (int rr = 0; rr < K; ++rr) {
            const float tv = __shfl(hm, srcbase + rr, 64);
            if (tv > m) { m = tv; fr = rr; }
        }
        const bool rowwin = (fr == myrr);
        // keep only the first (row-major) occurrence of the max
        bool seen = false;
#pragma unroll
        for (int c = 0; c < K; ++c) {
            const bool eq = (v[j * K + c] == m);
            if (!(rowwin && eq && !seen)) v[j * K + c] = 0.0f;
            seen = seen || eq;
        }
    }
}

__global__ __launch_bounds__(256) void pooling_nms_kernel(
    const float* __restrict__ x, float* __restrict__ out) {
    const int t = threadIdx.x;
    const int w = t >> 6;               // wave 0..3
    const int lane = t & 63;
    const int h = lane >> 5;            // half: which 30-col segment
    const int r = lane & 31;            // row 0..31 (30,31 inactive)
    const int rc = (r < 30) ? r : 29;   // clamped for compute-only lanes

    const int col0 = blockIdx.x * 240 + w * 60 + h * 30;
    const size_t base = (size_t)blockIdx.z * (IMG_H * (size_t)IMG_W) +
                        (size_t)(blockIdx.y * 30 + rc) * IMG_W + col0;
    const float* src = x + base;
    float* dst = out + base;

    float v[30];
    if (r < 30) {
        if (h == 0) {  // 16B-aligned start
#pragma unroll
            for (int q = 0; q < 7; ++q)
                *reinterpret_cast<float4*>(&v[4 * q]) =
                    *reinterpret_cast<const float4*>(src + 4 * q);
            *reinterpret_cast<float2*>(&v[28]) =
                *reinterpret_cast<const float2*>(src + 28);
        } else {       // start == 8 mod 16: float2 then aligned float4s
            *reinterpret_cast<float2*>(&v[0]) =
                *reinterpret_cast<const float2*>(src);
#pragma unroll
            for (int q = 0; q < 7; ++q)
                *reinterpret_cast<float4*>(&v[2 + 4 * q]) =
                    *reinterpret_cast<const float4*>(src + 2 + 4 * q);
        }
    }
    // lanes 30,31: v undefined -> pure-ALU garbage below, never sourced by
    // shuffles (srcbase+rr <= 29+32h), never stored.

    stage<3>(v, rc, h);
    stage<5>(v, rc, h);
    stage<6>(v, rc, h);

    if (r < 30) {
        if (h == 0) {
#pragma unroll
            for (int q = 0; q < 7; ++q)
                *reinterpret_cast<float4*>(dst + 4 * q) =
                    *reinterpret_cast<const float4*>(&v[4 * q]);
            *reinterpret_cast<float2*>(dst + 28) =
                *reinterpret_cast<const float2*>(&v[28]);
        } else {
            *reinterpret_cast<float2*>(dst) =
                *reinterpret_cast<const float2*>(&v[0]);
#pragma unroll
            for (int q = 0; q < 7; ++q)
                *reinterpret_cast<float4*>(dst + 2 + 4 * q) =
                    *reinterpret_cast<const float4*>(&v[2 + 4 * q]);
        }
    }
}

extern "C" void kernel_launch(void* const* d_in, const int* in_sizes, int n_in,
                              void* d_out, int out_size, void* d_ws, size_t ws_size,
                              hipStream_t stream) {
    const float* x = (const float*)d_in[0];
    float* out = (float*)d_out;
    dim3 grid(IMG_W / 240, IMG_H / 30, 16);  // 8 x 36 x 16 = 4608 blocks
    pooling_nms_kernel<<<grid, 256, 0, stream>>>(x, out);
}

// Round 6
// 241.689 us; speedup vs baseline: 1.1943x; 1.1943x over previous
//
#include <hip/hip_runtime.h>
#include <stdint.h>

// PoolingNms: 3 chained pool/unpool passes (k=3,5,6) on 16x1x1080x1920 fp32.
// lcm(3,5,6)=30 -> every 30x30 tile independent.
//
// Cross-round law (R0..R5): rate = independent waves x coalesced transactions.
//  R0/R2/R4 (LDS+barriers, coalesced): 96-100us, 2.05 TB/s - barrier duty cycle.
//  R1 (barrier-free, 30-wide tiles): 2.6 TB/s rate but 1.44x traffic.
//  R5 (barrier-free, row-per-lane): occupancy 57% but UNCOALESCED loads
//    (64 lanes x stride 7680B per instr -> ~4x transaction amplification),
//    VALUBusy 13%, 1.65 TB/s.
//
// Round 6: lane = COLUMN, registers = rows. Both properties at once:
//  - wave owns 30 rows x 60 cols; lane c holds its column in v[30].
//  - loads/stores: per row, lanes 0..59 touch 240 CONTIGUOUS bytes
//    (global_load_dword, fully coalesced); 30 loads = 30-deep MLP.
//  - vertical K-max: thread-local (rows are registers, zero communication).
//  - horizontal K-max: __shfl over K consecutive lanes (window cols tile the
//    60 lanes exactly; groups never cross lane 59).
//  - no LDS, no barriers, no runtime-indexed register arrays.
//  - write-merge: block = 4 waves = 240 cols = 960 B/row, 64B-line-aligned
//    (960*bx % 64 == 0); partial lines shared only intra-block (same CU).
// First-occurrence (== jnp.argmax row-major) via bitmasks, exact fp equality:
//  M = window max; mask bit r = (v[r]==M); comb = OR over group cols;
//  R = ffs(comb); winner = my bit R set && no earlier col has bit R.

#define IMG_H 1080
#define IMG_W 1920

template <int K>
__device__ __forceinline__ void stage(float (&v)[30], int cg, int cc) {
    constexpr int NW = 30 / K;  // windows along the 30 rows
#pragma unroll
    for (int j = 0; j < NW; ++j) {
        // vertical K-max of my column (thread-local)
        float vm = v[j * K];
#pragma unroll
        for (int rr = 1; rr < K; ++rr) vm = fmaxf(vm, v[j * K + rr]);
        // horizontal max over the K columns of the group
        float M = vm;
#pragma unroll
        for (int q = 0; q < K; ++q) M = fmaxf(M, __shfl(vm, cg + q, 64));
        // equality mask over my column's K rows (exact fp compare)
        unsigned mask = 0u;
#pragma unroll
        for (int rr = 0; rr < K; ++rr)
            mask |= (v[j * K + rr] == M) ? (1u << rr) : 0u;
        // combine masks across the group; prefix = cols strictly before mine
        unsigned comb = 0u, pre = 0u;
#pragma unroll
        for (int q = 0; q < K; ++q) {
            const unsigned mq = (unsigned)__shfl((int)mask, cg + q, 64);
            comb |= mq;
            pre |= (q < cc) ? mq : 0u;
        }
        const int R = __ffs(comb) - 1;  // first row containing the max
        const bool win = ((mask >> R) & 1u) != 0u && ((pre >> R) & 1u) == 0u;
        // keep only the first (row-major) occurrence of the max
#pragma unroll
        for (int rr = 0; rr < K; ++rr)
            v[j * K + rr] = (win && rr == R) ? M : 0.0f;
    }
}

__global__ __launch_bounds__(256, 6) void pooling_nms_kernel(
    const float* __restrict__ x, float* __restrict__ out) {
    const int t = threadIdx.x;
    const int w = t >> 6;                  // wave 0..3 -> 60-col sub-strip
    const int lane = t & 63;
    const int c = (lane < 60) ? lane : 59; // idle lanes mirror col 59: their
                                           // loads are in-bounds duplicates,
                                           // compute is identical, stores are
                                           // predicated off. Groups never
                                           // source lanes >= 60.
    const int col0 = blockIdx.x * 240 + w * 60;
    const size_t base = (size_t)blockIdx.z * (IMG_H * (size_t)IMG_W) +
                        (size_t)(blockIdx.y * 30) * IMG_W + col0 + c;
    const float* src = x + base;
    float* dst = out + base;

    // Coalesced column load: per row, lanes 0..59 = 240 contiguous bytes.
    float v[30];
#pragma unroll
    for (int r = 0; r < 30; ++r) v[r] = src[(size_t)r * IMG_W];

    {   // stage K=3: groups {0,1,2},{3,4,5},... within 60 lanes
        const int cg = (c / 3) * 3;
        stage<3>(v, cg, c - cg);
    }
    {   // stage K=5
        const int cg = (c / 5) * 5;
        stage<5>(v, cg, c - cg);
    }
    {   // stage K=6
        const int cg = (c / 6) * 6;
        stage<6>(v, cg, c - cg);
    }

    if (lane < 60) {
#pragma unroll
        for (int r = 0; r < 30; ++r) dst[(size_t)r * IMG_W] = v[r];
    }
}

extern "C" void kernel_launch(void* const* d_in, const int* in_sizes, int n_in,
                              void* d_out, int out_size, void* d_ws, size_t ws_size,
                              hipStream_t stream) {
    const float* x = (const float*)d_in[0];
    float* out = (float*)d_out;
    dim3 grid(IMG_W / 240, IMG_H / 30, 16);  // 8 x 36 x 16 = 4608 blocks
    pooling_nms_kernel<<<grid, 256, 0, stream>>>(x, out);
}